// Round 9
// baseline (462.826 us; speedup 1.0000x reference)
//
#include <hip/hip_runtime.h>
#include <stdint.h>
#include <stddef.h>

typedef __attribute__((ext_vector_type(8))) short short8;
typedef __attribute__((ext_vector_type(4))) float f32x4;

// ---- sizes ----
// x: (8, 64, 32, 32, 96) f32.  NH=4, hd=16, scale = 0.25
// intermediates q,k,v: bf16, per (b,o): d-plane layout [d=0..95][pos=h*32+w] (2KB planes)
#define PER_BO 98304            // 96 d * 1024 pos ushorts per (b,o)

__device__ __forceinline__ unsigned int cvtpk(float lo, float hi) {
    unsigned int r;
    asm("v_cvt_pk_bf16_f32 %0, %1, %2" : "=v"(r) : "v"(lo), "v"(hi));
    return r;
}

// ============================ Kernel 1: projection GEMM (MFMA) ============================
// C[384 pos, 192 out] per block (4 hw columns). A direct-to-reg, W bf16 LDS (swizzled).
// C routed through LDS Cb pivoted to [o][d][pos4] so stream-out writes d-plane layout.
// Chunked XCD swizzle: 8 line-sharing consecutive blocks land on one XCD for L2 merge.
__global__ __launch_bounds__(512, 2) void proj_mfma(
    const float* __restrict__ x, const float* __restrict__ w_sr, const float* __restrict__ b_sr,
    const float* __restrict__ Wq, const float* __restrict__ bq,
    const float* __restrict__ Wkv, const float* __restrict__ bkv,
    unsigned short* __restrict__ qb, unsigned short* __restrict__ kb, unsigned short* __restrict__ vb)
{
    __shared__ unsigned short Wh[12288];
    __shared__ float bl[192];
    __shared__ unsigned short Cb[2 * 6208];   // [buf][o_l:stride 388][d*4 + hwl]

    int t = threadIdx.x;
    int bidx = blockIdx.x;
    // chunked XCD swizzle: XCD x gets logical blocks [x*256, (x+1)*256)
    int lf = (bidx & 7) * 256 + (bidx >> 3);
    int b = lf >> 8;
    int blk = lf & 255;              // 4 hw columns each

    int lane = t & 63;
    int wvi = t >> 6;                // 0..7; wave owns pos-tiles wvi*3 .. wvi*3+2
    int lr = lane & 15, hk = lane >> 4;

    // ---- A: load x straight into registers (fragment layout) ----
    const float* xb = x + (size_t)b * 6291456 + (size_t)blk * 384;
    float af[3][16];
#pragma unroll
    for (int pi = 0; pi < 3; ++pi) {
        int pt = wvi * 3 + pi;
        const float* xp = xb + (size_t)(hk * 8) * 98304 + pt * 16 + lr;
#pragma unroll
        for (int j = 0; j < 8; ++j) {
            af[pi][j]     = xp[(size_t)j * 98304];
            af[pi][8 + j] = xp[(size_t)(32 + j) * 98304];
        }
    }

    // ---- stage W_eff (bf16, swizzled) ----
#pragma unroll
    for (int i = 0; i < 6; ++i) {
        int qi = t + i * 512;
        int o = qi >> 4;
        int cq = qi & 15;
        int c = cq * 4;
        float4 wv4;
        if (o < 64) wv4 = *reinterpret_cast<const float4*>(Wq + o * 64 + c);
        else {
            wv4 = *reinterpret_cast<const float4*>(Wkv + (o - 64) * 64 + c);
            float4 sr = *reinterpret_cast<const float4*>(w_sr + c);
            wv4.x *= sr.x; wv4.y *= sr.y; wv4.z *= sr.z; wv4.w *= sr.w;
        }
        uint2 pk; pk.x = cvtpk(wv4.x, wv4.y); pk.y = cvtpk(wv4.z, wv4.w);
        int sw = (cq >> 1) ^ (o & 7);
        *reinterpret_cast<uint2*>(&Wh[o * 64 + sw * 8 + (cq & 1) * 4]) = pk;
    }
    if (t < 192) {
        float s;
        if (t < 64) s = bq[t];
        else {
            s = bkv[t - 64];
            for (int c = 0; c < 64; ++c) s += Wkv[(t - 64) * 64 + c] * b_sr[c];
        }
        bl[t] = s;
    }
    __syncthreads();

    // ---- convert A to hi/lo bf16 fragments ----
    short8 ahf[3][2], alf[3][2];
#pragma unroll
    for (int pi = 0; pi < 3; ++pi) {
#pragma unroll
        for (int half = 0; half < 2; ++half) {
            union { unsigned int u[4]; short8 v; } H, L;
#pragma unroll
            for (int q = 0; q < 4; ++q) {
                float f0 = af[pi][half * 8 + 2 * q];
                float f1 = af[pi][half * 8 + 2 * q + 1];
                unsigned int hp = cvtpk(f0, f1);
                float h0 = __uint_as_float(hp << 16);
                float h1 = __uint_as_float(hp & 0xffff0000u);
                H.u[q] = hp;
                L.u[q] = cvtpk(f0 - h0, f1 - h1);
            }
            ahf[pi][half] = H.v; alf[pi][half] = L.v;
        }
    }

    // ---- per-pt Cb write offsets: quad = 4 consecutive d of one pos ----
    // Cb[o_l*388 + (d0+i)*4 + hwl]
    int wo[3];
#pragma unroll
    for (int pi = 0; pi < 3; ++pi) {
        int m0 = (wvi * 3 + pi) * 16 + hk * 4;
        int hwl = m0 / 96;
        int d0 = m0 - hwl * 96;
        wo[pi] = lr * 388 + d0 * 4 + hwl;
    }

    // ---- stream-out decode: chunk = (o_l, d, pos 0..3) = uint2 ----
    int so_po[3], so_lo[3];
#pragma unroll
    for (int i = 0; i < 3; ++i) {
        int flat = i * 512 + t;        // 0..1535
        int o_l = flat / 96;
        int d = flat - o_l * 96;
        so_po[i] = o_l * PER_BO + d * 1024 + blk * 4;
        so_lo[i] = o_l * 388 + d * 4;
    }

    float biasv[12];
#pragma unroll
    for (int ot = 0; ot < 12; ++ot) biasv[ot] = bl[ot * 16 + lr];

    f32x4 zero4 = {0.f, 0.f, 0.f, 0.f};
    int s7 = lr & 7;

#pragma unroll
    for (int ot = 0; ot < 12; ++ot) {
        unsigned short* cb = Cb + (ot & 1) * 6208;
        {
            int o = ot * 16 + lr;
            const unsigned short* wr = &Wh[o * 64];
            short8 b0 = *reinterpret_cast<const short8*>(wr + ((hk ^ s7) * 8));
            short8 b1 = *reinterpret_cast<const short8*>(wr + (((hk + 4) ^ s7) * 8));
            float bo = biasv[ot];
#pragma unroll
            for (int pi = 0; pi < 3; ++pi) {
                f32x4 acc = __builtin_amdgcn_mfma_f32_16x16x32_bf16(ahf[pi][0], b0, zero4, 0, 0, 0);
                acc = __builtin_amdgcn_mfma_f32_16x16x32_bf16(ahf[pi][1], b1, acc, 0, 0, 0);
                acc = __builtin_amdgcn_mfma_f32_16x16x32_bf16(alf[pi][0], b0, acc, 0, 0, 0);
                acc = __builtin_amdgcn_mfma_f32_16x16x32_bf16(alf[pi][1], b1, acc, 0, 0, 0);
                unsigned int u0 = cvtpk(acc[0] + bo, acc[1] + bo);
                unsigned int u1 = cvtpk(acc[2] + bo, acc[3] + bo);
                cb[wo[pi]]      = (unsigned short)u0;
                cb[wo[pi] + 4]  = (unsigned short)(u0 >> 16);
                cb[wo[pi] + 8]  = (unsigned short)u1;
                cb[wo[pi] + 12] = (unsigned short)(u1 >> 16);
            }
        }
        __syncthreads();
        {
            int sel = ot >> 2;
            unsigned short* base =
                (sel == 0 ? qb : (sel == 1 ? kb : vb)) + (size_t)(b * 64 + (ot & 3) * 16) * PER_BO;
#pragma unroll
            for (int i = 0; i < 3; ++i)
                *reinterpret_cast<uint2*>(base + so_po[i]) =
                    *reinterpret_cast<const uint2*>(&cb[so_lo[i]]);
        }
    }
}

// ============================ Kernel 2: attention (direct-reg, d-planes) ============================
// Block = (b, oc, h-half) with R8 XCD pair-swizzle. 512 threads = 8 waves; wave dsub owns
// dl=dsub of each chunk. Pass1: Q/K frags read DIRECTLY from global d-planes (coalesced
// uint4/lane) -> zero LDS, zero barriers. Pass2: each wave stages its own 2KB V-plane into
// wave-private LDS (transposed), P via wave-private Pb; Osf double-buffered -> 64B out
// stores per 2-ch with 2 barriers per pair. Total barriers ~15.
// LDS 61440 static: Vw 8x2304B @0, Pb 8x1152B @18432, Osf2 2x16896 @27648
//   (lred 16896 + rlb 2112 alias the Osf region between passes).
__global__ __launch_bounds__(512, 4) void attn_kernel(
    const unsigned short* __restrict__ qb, const unsigned short* __restrict__ kb,
    const unsigned short* __restrict__ vb,
    const float* __restrict__ gamma, const float* __restrict__ beta,
    float* __restrict__ out)
{
    __shared__ char smem[61440];
    unsigned short* Vw = (unsigned short*)smem;            // per-wave [w:32][g: stride 36]
    unsigned short* Pb = (unsigned short*)(smem + 18432);  // per-wave [h:16][g: stride 36]
    float* Osf  = (float*)(smem + 27648);                  // 2 bufs x 8 planes x 528
    float* lred = (float*)(smem + 27648);
    float* rlb  = (float*)(smem + 27648 + 16896);

    int t = threadIdx.x;
    int l = t & 63;
    int dsub = t >> 6;
    int lr = l & 15, hk = l >> 4;

    // XCD pair swizzle (both halves of (b,oc) on same XCD, concurrent)
    int id = blockIdx.x;
    int xcd = id & 7;
    int k7 = id >> 3;
    int p = xcd + 8 * (k7 >> 1);
    int half = k7 & 1;
    int oc = p & 63;
    int b = p >> 6;
    int n = oc >> 4;

    const unsigned short* qp = qb + (size_t)(b * 64 + oc) * PER_BO;
    const unsigned short* kp = kb + (size_t)(b * 64 + oc) * PER_BO;
    const unsigned short* vp = vb + (size_t)(b * 64 + oc) * PER_BO;

    float gm = gamma[n], bt = beta[n];
    float decv[8];
#pragma unroll
    for (int gb = 0; gb < 2; ++gb)
#pragma unroll
        for (int r = 0; r < 4; ++r) {
            int hh = half * 16 + hk * 4 + r;
            int gg = gb * 16 + lr;
            float dc = 2.0f * fabsf((float)(hh - gg)) * gm + bt;
            float sp = fmaxf(dc, 0.0f) + log1pf(__expf(-fabsf(dc)));
            decv[gb * 4 + r] = __expf(-sp);
        }

    const float scale = 0.25f;
    f32x4 zero4 = {0.f, 0.f, 0.f, 0.f};

    unsigned int ep[48];
    float lacc[8] = {0.f, 0.f, 0.f, 0.f, 0.f, 0.f, 0.f, 0.f};

    // ---------------- PASS 1: direct-reg QK^T -> E + partial l (no LDS, no barriers) ----------------
    int qoff  = half * 512 + lr * 32 + hk * 8;
    int koff0 = lr * 32 + hk * 8;
    int koff1 = koff0 + 512;

    uint4 qv[2], k0v[2], k1v[2];
    {
        int b0p = dsub * 1024;
        qv[0]  = *reinterpret_cast<const uint4*>(qp + b0p + qoff);
        k0v[0] = *reinterpret_cast<const uint4*>(kp + b0p + koff0);
        k1v[0] = *reinterpret_cast<const uint4*>(kp + b0p + koff1);
        int b1p = (8 + dsub) * 1024;
        qv[1]  = *reinterpret_cast<const uint4*>(qp + b1p + qoff);
        k0v[1] = *reinterpret_cast<const uint4*>(kp + b1p + koff0);
        k1v[1] = *reinterpret_cast<const uint4*>(kp + b1p + koff1);
    }

#pragma unroll
    for (int ch = 0; ch < 12; ++ch) {
        int s = ch & 1;
        union { uint4 u; short8 v; } A, B0, B1;
        A.u = qv[s]; B0.u = k0v[s]; B1.u = k1v[s];
        f32x4 s0 = __builtin_amdgcn_mfma_f32_16x16x32_bf16(A.v, B0.v, zero4, 0, 0, 0);
        f32x4 s1 = __builtin_amdgcn_mfma_f32_16x16x32_bf16(A.v, B1.v, zero4, 0, 0, 0);
        if (ch < 10) {
            int bp = ((ch + 2) * 8 + dsub) * 1024;
            qv[s]  = *reinterpret_cast<const uint4*>(qp + bp + qoff);
            k0v[s] = *reinterpret_cast<const uint4*>(kp + bp + koff0);
            k1v[s] = *reinterpret_cast<const uint4*>(kp + bp + koff1);
        }
        float e[8];
#pragma unroll
        for (int r = 0; r < 4; ++r) {
            e[r]     = __expf(s0[r] * scale + decv[r]);
            e[4 + r] = __expf(s1[r] * scale + decv[4 + r]);
        }
#pragma unroll
        for (int i = 0; i < 8; ++i) lacc[i] += e[i];
        ep[ch * 4 + 0] = cvtpk(e[0], e[1]);
        ep[ch * 4 + 1] = cvtpk(e[2], e[3]);
        ep[ch * 4 + 2] = cvtpk(e[4], e[5]);
        ep[ch * 4 + 3] = cvtpk(e[6], e[7]);
    }

    // ---------------- l reduction (only cross-wave communication) ----------------
#pragma unroll
    for (int i = 0; i < 8; ++i)
        lred[dsub * 528 + (hk * 4 + (i & 3)) * 33 + (i >> 2) * 16 + lr] = lacc[i];
    __syncthreads();
    {
        float rsum = 0.f;
#pragma unroll
        for (int s = 0; s < 8; ++s) rsum += lred[s * 528 + (t >> 5) * 33 + (t & 31)];
        rlb[(t >> 5) * 33 + (t & 31)] = 1.0f / rsum;
    }
    __syncthreads();
    float rl8[8];
#pragma unroll
    for (int i = 0; i < 8; ++i)
        rl8[i] = rlb[(hk * 4 + (i & 3)) * 33 + (i >> 2) * 16 + lr];
    __syncthreads();

    // ---------------- PASS 2: wave-private V stage + P -> PV -> out ----------------
    int vgoff = l * 16;                       // lane's 16-short slice of the 1024-short plane
    int vwbase = dsub * 1152 + ((l & 1) * 16) * 36 + (l >> 1);  // transposed write base
    unsigned short* Pw = Pb + dsub * 576;

    uint4 vv0[2], vv1[2];
    {
        int b0p = dsub * 1024 + vgoff;
        vv0[0] = *reinterpret_cast<const uint4*>(vp + b0p);
        vv1[0] = *reinterpret_cast<const uint4*>(vp + b0p + 8);
        int b1p = (8 + dsub) * 1024 + vgoff;
        vv0[1] = *reinterpret_cast<const uint4*>(vp + b1p);
        vv1[1] = *reinterpret_cast<const uint4*>(vp + b1p + 8);
    }

    size_t obase0 = ((size_t)(b * 64 + oc) * 1024 + half * 512 + t) * 96;

#pragma unroll
    for (int ch = 0; ch < 12; ++ch) {
        int s = ch & 1;
        // stage V-plane transposed into wave-private Vw
        {
            union { uint4 u; unsigned short e[8]; } V0, V1;
            V0.u = vv0[s]; V1.u = vv1[s];
#pragma unroll
            for (int i = 0; i < 8; ++i) Vw[vwbase + i * 36] = V0.e[i];
#pragma unroll
            for (int i = 0; i < 8; ++i) Vw[vwbase + (i + 8) * 36] = V1.e[i];
        }
        // build P into wave-private Pw
#pragma unroll
        for (int gb = 0; gb < 2; ++gb)
#pragma unroll
            for (int rp = 0; rp < 2; ++rp) {
                unsigned int u = ep[ch * 4 + gb * 2 + rp];
                float p0 = __uint_as_float(u << 16)         * rl8[gb * 4 + rp * 2];
                float p1 = __uint_as_float(u & 0xffff0000u) * rl8[gb * 4 + rp * 2 + 1];
                unsigned int pk = cvtpk(p0, p1);
                Pw[(hk * 4 + rp * 2) * 36 + gb * 16 + lr]     = (unsigned short)pk;
                Pw[(hk * 4 + rp * 2 + 1) * 36 + gb * 16 + lr] = (unsigned short)(pk >> 16);
            }
        if (ch < 10) {
            int bp = ((ch + 2) * 8 + dsub) * 1024 + vgoff;
            vv0[s] = *reinterpret_cast<const uint4*>(vp + bp);
            vv1[s] = *reinterpret_cast<const uint4*>(vp + bp + 8);
        }
        asm volatile("s_waitcnt lgkmcnt(0)" ::: "memory");
        __builtin_amdgcn_sched_barrier(0);
        short8 pa  = *reinterpret_cast<const short8*>(Pw + lr * 36 + hk * 8);
        short8 vb0 = *reinterpret_cast<const short8*>(Vw + dsub * 1152 + lr * 36 + hk * 8);
        short8 vb1 = *reinterpret_cast<const short8*>(Vw + dsub * 1152 + (16 + lr) * 36 + hk * 8);
        f32x4 o0 = __builtin_amdgcn_mfma_f32_16x16x32_bf16(pa, vb0, zero4, 0, 0, 0);
        f32x4 o1 = __builtin_amdgcn_mfma_f32_16x16x32_bf16(pa, vb1, zero4, 0, 0, 0);
        float* Od = Osf + s * 4224 + dsub * 528;
#pragma unroll
        for (int r = 0; r < 4; ++r) {
            Od[(hk * 4 + r) * 33 + lr]      = o0[r];
            Od[(hk * 4 + r) * 33 + 16 + lr] = o1[r];
        }
        if (ch & 1) {
            __syncthreads();
            int lidx = (t >> 5) * 33 + (t & 31);
            float4 q0, q1, q2, q3;
            q0.x = Osf[0 * 528 + lidx]; q0.y = Osf[1 * 528 + lidx];
            q0.z = Osf[2 * 528 + lidx]; q0.w = Osf[3 * 528 + lidx];
            q1.x = Osf[4 * 528 + lidx]; q1.y = Osf[5 * 528 + lidx];
            q1.z = Osf[6 * 528 + lidx]; q1.w = Osf[7 * 528 + lidx];
            q2.x = Osf[4224 + 0 * 528 + lidx]; q2.y = Osf[4224 + 1 * 528 + lidx];
            q2.z = Osf[4224 + 2 * 528 + lidx]; q2.w = Osf[4224 + 3 * 528 + lidx];
            q3.x = Osf[4224 + 4 * 528 + lidx]; q3.y = Osf[4224 + 5 * 528 + lidx];
            q3.z = Osf[4224 + 6 * 528 + lidx]; q3.w = Osf[4224 + 7 * 528 + lidx];
            float* po = out + obase0 + (ch >> 1) * 16;
            *reinterpret_cast<float4*>(po)      = q0;
            *reinterpret_cast<float4*>(po + 4)  = q1;
            *reinterpret_cast<float4*>(po + 8)  = q2;
            *reinterpret_cast<float4*>(po + 12) = q3;
            __syncthreads();
        }
    }
}

extern "C" void kernel_launch(void* const* d_in, const int* in_sizes, int n_in,
                              void* d_out, int out_size, void* d_ws, size_t ws_size,
                              hipStream_t stream) {
    const float* x     = (const float*)d_in[0];
    const float* w_sr  = (const float*)d_in[1];
    const float* b_sr  = (const float*)d_in[2];
    const float* Wq    = (const float*)d_in[3];
    const float* bq    = (const float*)d_in[4];
    const float* Wkv   = (const float*)d_in[5];
    const float* bkv   = (const float*)d_in[6];
    const float* gamma = (const float*)d_in[7];
    const float* beta  = (const float*)d_in[8];
    float* out = (float*)d_out;

    unsigned short* qb = (unsigned short*)d_ws;
    unsigned short* kb = qb + (size_t)50331648;
    unsigned short* vb = kb + (size_t)50331648;

    proj_mfma<<<2048, 512, 0, stream>>>(x, w_sr, b_sr, Wq, bq, Wkv, bkv, qb, kb, vb);

    attn_kernel<<<1024, 512, 0, stream>>>(qb, kb, vb, gamma, beta, out);
}

// Round 10
// 407.481 us; speedup vs baseline: 1.1358x; 1.1358x over previous
//
#include <hip/hip_runtime.h>
#include <stdint.h>
#include <stddef.h>

typedef __attribute__((ext_vector_type(8))) short short8;
typedef __attribute__((ext_vector_type(4))) float f32x4;

// ---- sizes ----
// x: (8, 64, 32, 32, 96) f32.  NH=4, hd=16, scale = 0.25
// intermediates q,k,v: bf16, per (b,o): BRICK layout [brick=hw/4][d][hw%4]
//   short addr = (b*64+o)*98304 + brick*384 + d*4 + (hw&3).  brick = h*8 + w/4.
#define PER_BO 98304

__device__ __forceinline__ unsigned int cvtpk(float lo, float hi) {
    unsigned int r;
    asm("v_cvt_pk_bf16_f32 %0, %1, %2" : "=v"(r) : "v"(lo), "v"(hi));
    return r;
}

// ============================ Kernel 1: projection GEMM (MFMA) ============================
// C[384 pos, 192 out] per block (4 hw columns). A direct-to-reg, W bf16 LDS (swizzled).
// C routed through LDS Cb [o][d][hw4]; stream-out now CONTIGUOUS per o (brick layout):
// full 64B lines, zero write amplification.
__global__ __launch_bounds__(512, 2) void proj_mfma(
    const float* __restrict__ x, const float* __restrict__ w_sr, const float* __restrict__ b_sr,
    const float* __restrict__ Wq, const float* __restrict__ bq,
    const float* __restrict__ Wkv, const float* __restrict__ bkv,
    unsigned short* __restrict__ qb, unsigned short* __restrict__ kb, unsigned short* __restrict__ vb)
{
    __shared__ unsigned short Wh[12288];
    __shared__ float bl[192];
    __shared__ unsigned short Cb[2 * 6208];   // [buf][o_l:stride 388][d*4 + hwl]

    int t = threadIdx.x;
    int bidx = blockIdx.x;
    int b = bidx >> 8;
    int blk = bidx & 255;              // 4 hw columns each; brick index == blk

    int lane = t & 63;
    int wvi = t >> 6;
    int lr = lane & 15, hk = lane >> 4;

    // ---- A: load x straight into registers (fragment layout) ----
    const float* xb = x + (size_t)b * 6291456 + (size_t)blk * 384;
    float af[3][16];
#pragma unroll
    for (int pi = 0; pi < 3; ++pi) {
        int pt = wvi * 3 + pi;
        const float* xp = xb + (size_t)(hk * 8) * 98304 + pt * 16 + lr;
#pragma unroll
        for (int j = 0; j < 8; ++j) {
            af[pi][j]     = xp[(size_t)j * 98304];
            af[pi][8 + j] = xp[(size_t)(32 + j) * 98304];
        }
    }

    // ---- stage W_eff (bf16, swizzled) ----
#pragma unroll
    for (int i = 0; i < 6; ++i) {
        int qi = t + i * 512;
        int o = qi >> 4;
        int cq = qi & 15;
        int c = cq * 4;
        float4 wv4;
        if (o < 64) wv4 = *reinterpret_cast<const float4*>(Wq + o * 64 + c);
        else {
            wv4 = *reinterpret_cast<const float4*>(Wkv + (o - 64) * 64 + c);
            float4 sr = *reinterpret_cast<const float4*>(w_sr + c);
            wv4.x *= sr.x; wv4.y *= sr.y; wv4.z *= sr.z; wv4.w *= sr.w;
        }
        uint2 pk; pk.x = cvtpk(wv4.x, wv4.y); pk.y = cvtpk(wv4.z, wv4.w);
        int sw = (cq >> 1) ^ (o & 7);
        *reinterpret_cast<uint2*>(&Wh[o * 64 + sw * 8 + (cq & 1) * 4]) = pk;
    }
    if (t < 192) {
        float s;
        if (t < 64) s = bq[t];
        else {
            s = bkv[t - 64];
            for (int c = 0; c < 64; ++c) s += Wkv[(t - 64) * 64 + c] * b_sr[c];
        }
        bl[t] = s;
    }
    __syncthreads();

    // ---- convert A to hi/lo bf16 fragments ----
    short8 ahf[3][2], alf[3][2];
#pragma unroll
    for (int pi = 0; pi < 3; ++pi) {
#pragma unroll
        for (int half = 0; half < 2; ++half) {
            union { unsigned int u[4]; short8 v; } H, L;
#pragma unroll
            for (int q = 0; q < 4; ++q) {
                float f0 = af[pi][half * 8 + 2 * q];
                float f1 = af[pi][half * 8 + 2 * q + 1];
                unsigned int hp = cvtpk(f0, f1);
                float h0 = __uint_as_float(hp << 16);
                float h1 = __uint_as_float(hp & 0xffff0000u);
                H.u[q] = hp;
                L.u[q] = cvtpk(f0 - h0, f1 - h1);
            }
            ahf[pi][half] = H.v; alf[pi][half] = L.v;
        }
    }

    // ---- per-pt Cb write offsets: Cb[o_l*388 + d0*4 + hwl] ----
    int wo[3];
#pragma unroll
    for (int pi = 0; pi < 3; ++pi) {
        int m0 = (wvi * 3 + pi) * 16 + hk * 4;
        int hwl = m0 / 96;
        int d0 = m0 - hwl * 96;
        wo[pi] = lr * 388 + d0 * 4 + hwl;
    }

    // ---- stream-out decode: per o fully contiguous 768B (brick layout) ----
    int so_po[3], so_lo[3];
#pragma unroll
    for (int i = 0; i < 3; ++i) {
        int flat = i * 512 + t;        // 0..1535
        int o_l = flat / 96;
        int d = flat - o_l * 96;
        so_po[i] = o_l * PER_BO + blk * 384 + d * 4;
        so_lo[i] = o_l * 388 + d * 4;
    }

    float biasv[12];
#pragma unroll
    for (int ot = 0; ot < 12; ++ot) biasv[ot] = bl[ot * 16 + lr];

    f32x4 zero4 = {0.f, 0.f, 0.f, 0.f};
    int s7 = lr & 7;

#pragma unroll
    for (int ot = 0; ot < 12; ++ot) {
        unsigned short* cb = Cb + (ot & 1) * 6208;
        {
            int o = ot * 16 + lr;
            const unsigned short* wr = &Wh[o * 64];
            short8 b0 = *reinterpret_cast<const short8*>(wr + ((hk ^ s7) * 8));
            short8 b1 = *reinterpret_cast<const short8*>(wr + (((hk + 4) ^ s7) * 8));
            float bo = biasv[ot];
#pragma unroll
            for (int pi = 0; pi < 3; ++pi) {
                f32x4 acc = __builtin_amdgcn_mfma_f32_16x16x32_bf16(ahf[pi][0], b0, zero4, 0, 0, 0);
                acc = __builtin_amdgcn_mfma_f32_16x16x32_bf16(ahf[pi][1], b1, acc, 0, 0, 0);
                acc = __builtin_amdgcn_mfma_f32_16x16x32_bf16(alf[pi][0], b0, acc, 0, 0, 0);
                acc = __builtin_amdgcn_mfma_f32_16x16x32_bf16(alf[pi][1], b1, acc, 0, 0, 0);
                unsigned int u0 = cvtpk(acc[0] + bo, acc[1] + bo);
                unsigned int u1 = cvtpk(acc[2] + bo, acc[3] + bo);
                cb[wo[pi]]      = (unsigned short)u0;
                cb[wo[pi] + 4]  = (unsigned short)(u0 >> 16);
                cb[wo[pi] + 8]  = (unsigned short)u1;
                cb[wo[pi] + 12] = (unsigned short)(u1 >> 16);
            }
        }
        __syncthreads();
        {
            int sel = ot >> 2;
            unsigned short* base =
                (sel == 0 ? qb : (sel == 1 ? kb : vb)) + (size_t)(b * 64 + (ot & 3) * 16) * PER_BO;
#pragma unroll
            for (int i = 0; i < 3; ++i)
                *reinterpret_cast<uint2*>(base + so_po[i]) =
                    *reinterpret_cast<const uint2*>(&cb[so_lo[i]]);
        }
    }
}

// ============================ Kernel 2: attention (direct-reg, bricks) ============================
// Same structure as R9 (zero-barrier pass1, wave-private pass2), but reads from brick layout:
// frag = 2 x 8B loads (bricks 768B apart); sibling waves consume the other d's of each line
// in the same iteration -> L1 absorbs.
__global__ __launch_bounds__(512, 4) void attn_kernel(
    const unsigned short* __restrict__ qb, const unsigned short* __restrict__ kb,
    const unsigned short* __restrict__ vb,
    const float* __restrict__ gamma, const float* __restrict__ beta,
    float* __restrict__ out)
{
    __shared__ char smem[61440];
    unsigned short* Vw = (unsigned short*)smem;            // per-wave [w:32][h: stride 36]
    unsigned short* Pb = (unsigned short*)(smem + 18432);
    float* Osf  = (float*)(smem + 27648);                  // 2 bufs x 8 planes x 528
    float* lred = (float*)(smem + 27648);
    float* rlb  = (float*)(smem + 27648 + 16896);

    int t = threadIdx.x;
    int l = t & 63;
    int dsub = t >> 6;
    int lr = l & 15, hk = l >> 4;

    // XCD pair swizzle (both halves of (b,oc) on same XCD, concurrent)
    int id = blockIdx.x;
    int xcd = id & 7;
    int k7 = id >> 3;
    int p = xcd + 8 * (k7 >> 1);
    int half = k7 & 1;
    int oc = p & 63;
    int b = p >> 6;
    int n = oc >> 4;

    const unsigned short* qp = qb + (size_t)(b * 64 + oc) * PER_BO;
    const unsigned short* kp = kb + (size_t)(b * 64 + oc) * PER_BO;
    const unsigned short* vp = vb + (size_t)(b * 64 + oc) * PER_BO;

    float gm = gamma[n], bt = beta[n];
    float decv[8];
#pragma unroll
    for (int gb = 0; gb < 2; ++gb)
#pragma unroll
        for (int r = 0; r < 4; ++r) {
            int hh = half * 16 + hk * 4 + r;
            int gg = gb * 16 + lr;
            float dc = 2.0f * fabsf((float)(hh - gg)) * gm + bt;
            float sp = fmaxf(dc, 0.0f) + log1pf(__expf(-fabsf(dc)));
            decv[gb * 4 + r] = __expf(-sp);
        }

    const float scale = 0.25f;
    f32x4 zero4 = {0.f, 0.f, 0.f, 0.f};

    unsigned int ep[48];
    float lacc[8] = {0.f, 0.f, 0.f, 0.f, 0.f, 0.f, 0.f, 0.f};

    // ---------------- PASS 1: direct-reg QK^T -> E + partial l (no LDS, no barriers) ----------------
    // lane base addrs (shorts); per-ch increment = 32 (8 d * 4)
    int bq0 = ((half * 16 + lr) * 8 + hk * 2) * 384 + dsub * 4;
    int bk0 = (lr * 8 + hk * 2) * 384 + dsub * 4;
    int bk1 = ((16 + lr) * 8 + hk * 2) * 384 + dsub * 4;

    uint2 qv[2][2], k0v[2][2], k1v[2][2];
#pragma unroll
    for (int s = 0; s < 2; ++s) {
        int off = s * 32;
        qv[s][0]  = *reinterpret_cast<const uint2*>(qp + bq0 + off);
        qv[s][1]  = *reinterpret_cast<const uint2*>(qp + bq0 + 384 + off);
        k0v[s][0] = *reinterpret_cast<const uint2*>(kp + bk0 + off);
        k0v[s][1] = *reinterpret_cast<const uint2*>(kp + bk0 + 384 + off);
        k1v[s][0] = *reinterpret_cast<const uint2*>(kp + bk1 + off);
        k1v[s][1] = *reinterpret_cast<const uint2*>(kp + bk1 + 384 + off);
    }

#pragma unroll
    for (int ch = 0; ch < 12; ++ch) {
        int s = ch & 1;
        union { unsigned int u[4]; short8 v; } A, B0, B1;
        A.u[0] = qv[s][0].x;  A.u[1] = qv[s][0].y;  A.u[2] = qv[s][1].x;  A.u[3] = qv[s][1].y;
        B0.u[0] = k0v[s][0].x; B0.u[1] = k0v[s][0].y; B0.u[2] = k0v[s][1].x; B0.u[3] = k0v[s][1].y;
        B1.u[0] = k1v[s][0].x; B1.u[1] = k1v[s][0].y; B1.u[2] = k1v[s][1].x; B1.u[3] = k1v[s][1].y;
        f32x4 s0 = __builtin_amdgcn_mfma_f32_16x16x32_bf16(A.v, B0.v, zero4, 0, 0, 0);
        f32x4 s1 = __builtin_amdgcn_mfma_f32_16x16x32_bf16(A.v, B1.v, zero4, 0, 0, 0);
        if (ch < 10) {
            int off = (ch + 2) * 32;
            qv[s][0]  = *reinterpret_cast<const uint2*>(qp + bq0 + off);
            qv[s][1]  = *reinterpret_cast<const uint2*>(qp + bq0 + 384 + off);
            k0v[s][0] = *reinterpret_cast<const uint2*>(kp + bk0 + off);
            k0v[s][1] = *reinterpret_cast<const uint2*>(kp + bk0 + 384 + off);
            k1v[s][0] = *reinterpret_cast<const uint2*>(kp + bk1 + off);
            k1v[s][1] = *reinterpret_cast<const uint2*>(kp + bk1 + 384 + off);
        }
        float e[8];
#pragma unroll
        for (int r = 0; r < 4; ++r) {
            e[r]     = __expf(s0[r] * scale + decv[r]);
            e[4 + r] = __expf(s1[r] * scale + decv[4 + r]);
        }
#pragma unroll
        for (int i = 0; i < 8; ++i) lacc[i] += e[i];
        ep[ch * 4 + 0] = cvtpk(e[0], e[1]);
        ep[ch * 4 + 1] = cvtpk(e[2], e[3]);
        ep[ch * 4 + 2] = cvtpk(e[4], e[5]);
        ep[ch * 4 + 3] = cvtpk(e[6], e[7]);
    }

    // ---------------- l reduction (only cross-wave communication) ----------------
#pragma unroll
    for (int i = 0; i < 8; ++i)
        lred[dsub * 528 + (hk * 4 + (i & 3)) * 33 + (i >> 2) * 16 + lr] = lacc[i];
    __syncthreads();
    {
        float rsum = 0.f;
#pragma unroll
        for (int s = 0; s < 8; ++s) rsum += lred[s * 528 + (t >> 5) * 33 + (t & 31)];
        rlb[(t >> 5) * 33 + (t & 31)] = 1.0f / rsum;
    }
    __syncthreads();
    float rl8[8];
#pragma unroll
    for (int i = 0; i < 8; ++i)
        rl8[i] = rlb[(hk * 4 + (i & 3)) * 33 + (i >> 2) * 16 + lr];
    __syncthreads();

    // ---------------- PASS 2: wave-private V stage + P -> PV -> out ----------------
    // lane covers bricks l*4+k (k=0..3): h = l>>1, w = (l&1)*16 + k*4 + 0..3
    int bv0 = (l * 4) * 384 + dsub * 4;
    int vwbase = dsub * 1152 + ((l & 1) * 16) * 36 + (l >> 1);
    unsigned short* Pw = Pb + dsub * 576;

    uint2 vvu[2][4];
#pragma unroll
    for (int s = 0; s < 2; ++s) {
        int off = s * 32;
#pragma unroll
        for (int k = 0; k < 4; ++k)
            vvu[s][k] = *reinterpret_cast<const uint2*>(vp + bv0 + k * 384 + off);
    }

    size_t obase0 = ((size_t)(b * 64 + oc) * 1024 + half * 512 + t) * 96;

#pragma unroll
    for (int ch = 0; ch < 12; ++ch) {
        int s = ch & 1;
        // stage V-plane transposed into wave-private Vw
        {
            union { unsigned int w[8]; unsigned short e[16]; } V;
#pragma unroll
            for (int k = 0; k < 4; ++k) { V.w[k * 2] = vvu[s][k].x; V.w[k * 2 + 1] = vvu[s][k].y; }
#pragma unroll
            for (int i = 0; i < 16; ++i) Vw[vwbase + i * 36] = V.e[i];
        }
        // build P into wave-private Pw
#pragma unroll
        for (int gb = 0; gb < 2; ++gb)
#pragma unroll
            for (int rp = 0; rp < 2; ++rp) {
                unsigned int u = ep[ch * 4 + gb * 2 + rp];
                float p0 = __uint_as_float(u << 16)         * rl8[gb * 4 + rp * 2];
                float p1 = __uint_as_float(u & 0xffff0000u) * rl8[gb * 4 + rp * 2 + 1];
                unsigned int pk = cvtpk(p0, p1);
                Pw[(hk * 4 + rp * 2) * 36 + gb * 16 + lr]     = (unsigned short)pk;
                Pw[(hk * 4 + rp * 2 + 1) * 36 + gb * 16 + lr] = (unsigned short)(pk >> 16);
            }
        if (ch < 10) {
            int off = (ch + 2) * 32;
#pragma unroll
            for (int k = 0; k < 4; ++k)
                vvu[s][k] = *reinterpret_cast<const uint2*>(vp + bv0 + k * 384 + off);
        }
        asm volatile("s_waitcnt lgkmcnt(0)" ::: "memory");
        __builtin_amdgcn_sched_barrier(0);
        short8 pa  = *reinterpret_cast<const short8*>(Pw + lr * 36 + hk * 8);
        short8 vb0 = *reinterpret_cast<const short8*>(Vw + dsub * 1152 + lr * 36 + hk * 8);
        short8 vb1 = *reinterpret_cast<const short8*>(Vw + dsub * 1152 + (16 + lr) * 36 + hk * 8);
        f32x4 o0 = __builtin_amdgcn_mfma_f32_16x16x32_bf16(pa, vb0, zero4, 0, 0, 0);
        f32x4 o1 = __builtin_amdgcn_mfma_f32_16x16x32_bf16(pa, vb1, zero4, 0, 0, 0);
        float* Od = Osf + s * 4224 + dsub * 528;
#pragma unroll
        for (int r = 0; r < 4; ++r) {
            Od[(hk * 4 + r) * 33 + lr]      = o0[r];
            Od[(hk * 4 + r) * 33 + 16 + lr] = o1[r];
        }
        if (ch & 1) {
            __syncthreads();
            int lidx = (t >> 5) * 33 + (t & 31);
            float4 q0, q1, q2, q3;
            q0.x = Osf[0 * 528 + lidx]; q0.y = Osf[1 * 528 + lidx];
            q0.z = Osf[2 * 528 + lidx]; q0.w = Osf[3 * 528 + lidx];
            q1.x = Osf[4 * 528 + lidx]; q1.y = Osf[5 * 528 + lidx];
            q1.z = Osf[6 * 528 + lidx]; q1.w = Osf[7 * 528 + lidx];
            q2.x = Osf[4224 + 0 * 528 + lidx]; q2.y = Osf[4224 + 1 * 528 + lidx];
            q2.z = Osf[4224 + 2 * 528 + lidx]; q2.w = Osf[4224 + 3 * 528 + lidx];
            q3.x = Osf[4224 + 4 * 528 + lidx]; q3.y = Osf[4224 + 5 * 528 + lidx];
            q3.z = Osf[4224 + 6 * 528 + lidx]; q3.w = Osf[4224 + 7 * 528 + lidx];
            float* po = out + obase0 + (ch >> 1) * 16;
            *reinterpret_cast<float4*>(po)      = q0;
            *reinterpret_cast<float4*>(po + 4)  = q1;
            *reinterpret_cast<float4*>(po + 8)  = q2;
            *reinterpret_cast<float4*>(po + 12) = q3;
            __syncthreads();
        }
    }
}

extern "C" void kernel_launch(void* const* d_in, const int* in_sizes, int n_in,
                              void* d_out, int out_size, void* d_ws, size_t ws_size,
                              hipStream_t stream) {
    const float* x     = (const float*)d_in[0];
    const float* w_sr  = (const float*)d_in[1];
    const float* b_sr  = (const float*)d_in[2];
    const float* Wq    = (const float*)d_in[3];
    const float* bq    = (const float*)d_in[4];
    const float* Wkv   = (const float*)d_in[5];
    const float* bkv   = (const float*)d_in[6];
    const float* gamma = (const float*)d_in[7];
    const float* beta  = (const float*)d_in[8];
    float* out = (float*)d_out;

    unsigned short* qb = (unsigned short*)d_ws;
    unsigned short* kb = qb + (size_t)50331648;
    unsigned short* vb = kb + (size_t)50331648;

    proj_mfma<<<2048, 512, 0, stream>>>(x, w_sr, b_sr, Wq, bq, Wkv, bkv, qb, kb, vb);

    attn_kernel<<<1024, 512, 0, stream>>>(qb, kb, vb, gamma, beta, out);
}

// Round 11
// 344.187 us; speedup vs baseline: 1.3447x; 1.1839x over previous
//
#include <hip/hip_runtime.h>
#include <stdint.h>
#include <stddef.h>

typedef __attribute__((ext_vector_type(8))) short short8;
typedef __attribute__((ext_vector_type(4))) float f32x4;

// ---- sizes ----
// x: (8, 64, 32, 32, 96) f32.  NH=4, hd=16, scale = 0.25
// intermediates q,k,v: bf16, per (b,o): d-plane layout [d=0..95][pos=h*32+w] (2KB planes)
#define PER_BO 98304            // 96 d * 1024 pos ushorts per (b,o)

__device__ __forceinline__ unsigned int cvtpk(float lo, float hi) {
    unsigned int r;
    asm("v_cvt_pk_bf16_f32 %0, %1, %2" : "=v"(r) : "v"(lo), "v"(hi));
    return r;
}

// ============================ Kernel 1: projection GEMM (MFMA) ============================
// Block = (b, h-row, d-group): covers ALL 32 w x 12 d of one h-row -> every 64B line of the
// d-plane output is fully produced by one block (full-line stores, zero amplification).
// M-mapping: m = w*12 + dd (w-major) keeps A-loads at ~8 segments/instr.
// bidx = dg*256 + h*8 + b => same-(b,h) d-group siblings share an XCD (x-line L2 merge).
__global__ __launch_bounds__(512, 2) void proj_mfma(
    const float* __restrict__ x, const float* __restrict__ w_sr, const float* __restrict__ b_sr,
    const float* __restrict__ Wq, const float* __restrict__ bq,
    const float* __restrict__ Wkv, const float* __restrict__ bkv,
    unsigned short* __restrict__ qb, unsigned short* __restrict__ kb, unsigned short* __restrict__ vb)
{
    __shared__ unsigned short Wh[12288];
    __shared__ float bl[192];
    __shared__ unsigned short Cb[2 * 6208];   // [buf][o_l: stride 388][m 384]

    int t = threadIdx.x;
    int bidx = blockIdx.x;
    int b = bidx & 7;
    int hrow = (bidx >> 3) & 31;
    int dg = bidx >> 8;                // 0..7, d-group of 12

    int lane = t & 63;
    int wvi = t >> 6;                  // 0..7; wave owns m-tiles wvi*3 .. wvi*3+2
    int lr = lane & 15, hk = lane >> 4;

    // ---- A: load x straight into registers (fragment layout) ----
    const float* xb = x + (size_t)b * 6291456 + hrow * 3072 + dg * 12;
    float af[3][16];
#pragma unroll
    for (int pi = 0; pi < 3; ++pi) {
        int m = (wvi * 3 + pi) * 16 + lr;
        int w = m / 12, dd = m - w * 12;
        const float* xp = xb + (size_t)(hk * 8) * 98304 + w * 96 + dd;
#pragma unroll
        for (int j = 0; j < 8; ++j) {
            af[pi][j]     = xp[(size_t)j * 98304];
            af[pi][8 + j] = xp[(size_t)(32 + j) * 98304];
        }
    }

    // ---- stage W_eff (bf16, swizzled) ----
#pragma unroll
    for (int i = 0; i < 6; ++i) {
        int qi = t + i * 512;
        int o = qi >> 4;
        int cq = qi & 15;
        int c = cq * 4;
        float4 wv4;
        if (o < 64) wv4 = *reinterpret_cast<const float4*>(Wq + o * 64 + c);
        else {
            wv4 = *reinterpret_cast<const float4*>(Wkv + (o - 64) * 64 + c);
            float4 sr = *reinterpret_cast<const float4*>(w_sr + c);
            wv4.x *= sr.x; wv4.y *= sr.y; wv4.z *= sr.z; wv4.w *= sr.w;
        }
        uint2 pk; pk.x = cvtpk(wv4.x, wv4.y); pk.y = cvtpk(wv4.z, wv4.w);
        int sw = (cq >> 1) ^ (o & 7);
        *reinterpret_cast<uint2*>(&Wh[o * 64 + sw * 8 + (cq & 1) * 4]) = pk;
    }
    if (t < 192) {
        float s;
        if (t < 64) s = bq[t];
        else {
            s = bkv[t - 64];
            for (int c = 0; c < 64; ++c) s += Wkv[(t - 64) * 64 + c] * b_sr[c];
        }
        bl[t] = s;
    }
    __syncthreads();

    // ---- convert A to hi/lo bf16 fragments ----
    short8 ahf[3][2], alf[3][2];
#pragma unroll
    for (int pi = 0; pi < 3; ++pi) {
#pragma unroll
        for (int half = 0; half < 2; ++half) {
            union { unsigned int u[4]; short8 v; } H, L;
#pragma unroll
            for (int q = 0; q < 4; ++q) {
                float f0 = af[pi][half * 8 + 2 * q];
                float f1 = af[pi][half * 8 + 2 * q + 1];
                unsigned int hp = cvtpk(f0, f1);
                float h0 = __uint_as_float(hp << 16);
                float h1 = __uint_as_float(hp & 0xffff0000u);
                H.u[q] = hp;
                L.u[q] = cvtpk(f0 - h0, f1 - h1);
            }
            ahf[pi][half] = H.v; alf[pi][half] = L.v;
        }
    }

    // ---- per-pt Cb write offsets: rows m0..m0+3 contiguous -> uint2 ----
    int wo[3];
#pragma unroll
    for (int pi = 0; pi < 3; ++pi)
        wo[pi] = lr * 388 + (wvi * 3 + pi) * 16 + hk * 4;

    // ---- stream-out decode: unit = 4 w at fixed (o, dd) = 8B, lanes contiguous ----
    int so_po[3], so_lo[3];
#pragma unroll
    for (int i = 0; i < 3; ++i) {
        int flat = i * 512 + t;        // 0..1535 = o_l(16) x dd(12) x w4(8)
        int o_l = flat / 96;
        int rem = flat - o_l * 96;
        int dd = rem >> 3;
        int w4 = rem & 7;
        so_po[i] = o_l * PER_BO + dd * 1024 + w4 * 4;
        so_lo[i] = o_l * 388 + w4 * 48 + dd;
    }

    float biasv[12];
#pragma unroll
    for (int ot = 0; ot < 12; ++ot) biasv[ot] = bl[ot * 16 + lr];

    f32x4 zero4 = {0.f, 0.f, 0.f, 0.f};
    int s7 = lr & 7;

#pragma unroll
    for (int ot = 0; ot < 12; ++ot) {
        unsigned short* cb = Cb + (ot & 1) * 6208;
        {
            int o = ot * 16 + lr;
            const unsigned short* wr = &Wh[o * 64];
            short8 b0 = *reinterpret_cast<const short8*>(wr + ((hk ^ s7) * 8));
            short8 b1 = *reinterpret_cast<const short8*>(wr + (((hk + 4) ^ s7) * 8));
            float bo = biasv[ot];
#pragma unroll
            for (int pi = 0; pi < 3; ++pi) {
                f32x4 acc = __builtin_amdgcn_mfma_f32_16x16x32_bf16(ahf[pi][0], b0, zero4, 0, 0, 0);
                acc = __builtin_amdgcn_mfma_f32_16x16x32_bf16(ahf[pi][1], b1, acc, 0, 0, 0);
                acc = __builtin_amdgcn_mfma_f32_16x16x32_bf16(alf[pi][0], b0, acc, 0, 0, 0);
                acc = __builtin_amdgcn_mfma_f32_16x16x32_bf16(alf[pi][1], b1, acc, 0, 0, 0);
                uint2 st;
                st.x = cvtpk(acc[0] + bo, acc[1] + bo);
                st.y = cvtpk(acc[2] + bo, acc[3] + bo);
                *reinterpret_cast<uint2*>(&cb[wo[pi]]) = st;
            }
        }
        __syncthreads();
        {
            int sel = ot >> 2;
            unsigned short* base =
                (sel == 0 ? qb : (sel == 1 ? kb : vb))
                + (size_t)(b * 64 + (ot & 3) * 16) * PER_BO + dg * 12288 + hrow * 32;
#pragma unroll
            for (int i = 0; i < 3; ++i) {
                const unsigned short* c = &cb[so_lo[i]];
                uint2 v;
                v.x = (unsigned int)c[0]  | ((unsigned int)c[12] << 16);
                v.y = (unsigned int)c[24] | ((unsigned int)c[36] << 16);
                *reinterpret_cast<uint2*>(base + so_po[i]) = v;
            }
        }
    }
}

// ============================ Kernel 2: attention (direct-reg, d-planes) ============================
// Verbatim R9 structure (measured ~127us): zero-barrier pass1 with direct coalesced frag reads,
// wave-private pass2 (V LDS transpose, no barriers), paired 64B out stores.
__global__ __launch_bounds__(512, 4) void attn_kernel(
    const unsigned short* __restrict__ qb, const unsigned short* __restrict__ kb,
    const unsigned short* __restrict__ vb,
    const float* __restrict__ gamma, const float* __restrict__ beta,
    float* __restrict__ out)
{
    __shared__ char smem[61440];
    unsigned short* Vw = (unsigned short*)smem;            // per-wave [w:32][h: stride 36]
    unsigned short* Pb = (unsigned short*)(smem + 18432);
    float* Osf  = (float*)(smem + 27648);                  // 2 bufs x 8 planes x 528
    float* lred = (float*)(smem + 27648);
    float* rlb  = (float*)(smem + 27648 + 16896);

    int t = threadIdx.x;
    int l = t & 63;
    int dsub = t >> 6;
    int lr = l & 15, hk = l >> 4;

    // XCD pair swizzle (both halves of (b,oc) on same XCD, concurrent)
    int id = blockIdx.x;
    int xcd = id & 7;
    int k7 = id >> 3;
    int p = xcd + 8 * (k7 >> 1);
    int half = k7 & 1;
    int oc = p & 63;
    int b = p >> 6;
    int n = oc >> 4;

    const unsigned short* qp = qb + (size_t)(b * 64 + oc) * PER_BO;
    const unsigned short* kp = kb + (size_t)(b * 64 + oc) * PER_BO;
    const unsigned short* vp = vb + (size_t)(b * 64 + oc) * PER_BO;

    float gm = gamma[n], bt = beta[n];
    float decv[8];
#pragma unroll
    for (int gb = 0; gb < 2; ++gb)
#pragma unroll
        for (int r = 0; r < 4; ++r) {
            int hh = half * 16 + hk * 4 + r;
            int gg = gb * 16 + lr;
            float dc = 2.0f * fabsf((float)(hh - gg)) * gm + bt;
            float sp = fmaxf(dc, 0.0f) + log1pf(__expf(-fabsf(dc)));
            decv[gb * 4 + r] = __expf(-sp);
        }

    const float scale = 0.25f;
    f32x4 zero4 = {0.f, 0.f, 0.f, 0.f};

    unsigned int ep[48];
    float lacc[8] = {0.f, 0.f, 0.f, 0.f, 0.f, 0.f, 0.f, 0.f};

    // ---------------- PASS 1: direct-reg QK^T -> E + partial l (no LDS, no barriers) ----------------
    int qoff  = half * 512 + lr * 32 + hk * 8;
    int koff0 = lr * 32 + hk * 8;
    int koff1 = koff0 + 512;

    uint4 qv[2], k0v[2], k1v[2];
    {
        int b0p = dsub * 1024;
        qv[0]  = *reinterpret_cast<const uint4*>(qp + b0p + qoff);
        k0v[0] = *reinterpret_cast<const uint4*>(kp + b0p + koff0);
        k1v[0] = *reinterpret_cast<const uint4*>(kp + b0p + koff1);
        int b1p = (8 + dsub) * 1024;
        qv[1]  = *reinterpret_cast<const uint4*>(qp + b1p + qoff);
        k0v[1] = *reinterpret_cast<const uint4*>(kp + b1p + koff0);
        k1v[1] = *reinterpret_cast<const uint4*>(kp + b1p + koff1);
    }

#pragma unroll
    for (int ch = 0; ch < 12; ++ch) {
        int s = ch & 1;
        union { uint4 u; short8 v; } A, B0, B1;
        A.u = qv[s]; B0.u = k0v[s]; B1.u = k1v[s];
        f32x4 s0 = __builtin_amdgcn_mfma_f32_16x16x32_bf16(A.v, B0.v, zero4, 0, 0, 0);
        f32x4 s1 = __builtin_amdgcn_mfma_f32_16x16x32_bf16(A.v, B1.v, zero4, 0, 0, 0);
        if (ch < 10) {
            int bp = ((ch + 2) * 8 + dsub) * 1024;
            qv[s]  = *reinterpret_cast<const uint4*>(qp + bp + qoff);
            k0v[s] = *reinterpret_cast<const uint4*>(kp + bp + koff0);
            k1v[s] = *reinterpret_cast<const uint4*>(kp + bp + koff1);
        }
        float e[8];
#pragma unroll
        for (int r = 0; r < 4; ++r) {
            e[r]     = __expf(s0[r] * scale + decv[r]);
            e[4 + r] = __expf(s1[r] * scale + decv[4 + r]);
        }
#pragma unroll
        for (int i = 0; i < 8; ++i) lacc[i] += e[i];
        ep[ch * 4 + 0] = cvtpk(e[0], e[1]);
        ep[ch * 4 + 1] = cvtpk(e[2], e[3]);
        ep[ch * 4 + 2] = cvtpk(e[4], e[5]);
        ep[ch * 4 + 3] = cvtpk(e[6], e[7]);
    }

    // ---------------- l reduction (only cross-wave communication) ----------------
#pragma unroll
    for (int i = 0; i < 8; ++i)
        lred[dsub * 528 + (hk * 4 + (i & 3)) * 33 + (i >> 2) * 16 + lr] = lacc[i];
    __syncthreads();
    {
        float rsum = 0.f;
#pragma unroll
        for (int s = 0; s < 8; ++s) rsum += lred[s * 528 + (t >> 5) * 33 + (t & 31)];
        rlb[(t >> 5) * 33 + (t & 31)] = 1.0f / rsum;
    }
    __syncthreads();
    float rl8[8];
#pragma unroll
    for (int i = 0; i < 8; ++i)
        rl8[i] = rlb[(hk * 4 + (i & 3)) * 33 + (i >> 2) * 16 + lr];
    __syncthreads();

    // ---------------- PASS 2: wave-private V stage + P -> PV -> out ----------------
    int vgoff = l * 16;
    int vwbase = dsub * 1152 + ((l & 1) * 16) * 36 + (l >> 1);
    unsigned short* Pw = Pb + dsub * 576;

    uint4 vv0[2], vv1[2];
    {
        int b0p = dsub * 1024 + vgoff;
        vv0[0] = *reinterpret_cast<const uint4*>(vp + b0p);
        vv1[0] = *reinterpret_cast<const uint4*>(vp + b0p + 8);
        int b1p = (8 + dsub) * 1024 + vgoff;
        vv0[1] = *reinterpret_cast<const uint4*>(vp + b1p);
        vv1[1] = *reinterpret_cast<const uint4*>(vp + b1p + 8);
    }

    size_t obase0 = ((size_t)(b * 64 + oc) * 1024 + half * 512 + t) * 96;

#pragma unroll
    for (int ch = 0; ch < 12; ++ch) {
        int s = ch & 1;
        {
            union { uint4 u; unsigned short e[8]; } V0, V1;
            V0.u = vv0[s]; V1.u = vv1[s];
#pragma unroll
            for (int i = 0; i < 8; ++i) Vw[vwbase + i * 36] = V0.e[i];
#pragma unroll
            for (int i = 0; i < 8; ++i) Vw[vwbase + (i + 8) * 36] = V1.e[i];
        }
#pragma unroll
        for (int gb = 0; gb < 2; ++gb)
#pragma unroll
            for (int rp = 0; rp < 2; ++rp) {
                unsigned int u = ep[ch * 4 + gb * 2 + rp];
                float p0 = __uint_as_float(u << 16)         * rl8[gb * 4 + rp * 2];
                float p1 = __uint_as_float(u & 0xffff0000u) * rl8[gb * 4 + rp * 2 + 1];
                unsigned int pk = cvtpk(p0, p1);
                Pw[(hk * 4 + rp * 2) * 36 + gb * 16 + lr]     = (unsigned short)pk;
                Pw[(hk * 4 + rp * 2 + 1) * 36 + gb * 16 + lr] = (unsigned short)(pk >> 16);
            }
        if (ch < 10) {
            int bp = ((ch + 2) * 8 + dsub) * 1024 + vgoff;
            vv0[s] = *reinterpret_cast<const uint4*>(vp + bp);
            vv1[s] = *reinterpret_cast<const uint4*>(vp + bp + 8);
        }
        asm volatile("s_waitcnt lgkmcnt(0)" ::: "memory");
        __builtin_amdgcn_sched_barrier(0);
        short8 pa  = *reinterpret_cast<const short8*>(Pw + lr * 36 + hk * 8);
        short8 vb0 = *reinterpret_cast<const short8*>(Vw + dsub * 1152 + lr * 36 + hk * 8);
        short8 vb1 = *reinterpret_cast<const short8*>(Vw + dsub * 1152 + (16 + lr) * 36 + hk * 8);
        f32x4 o0 = __builtin_amdgcn_mfma_f32_16x16x32_bf16(pa, vb0, zero4, 0, 0, 0);
        f32x4 o1 = __builtin_amdgcn_mfma_f32_16x16x32_bf16(pa, vb1, zero4, 0, 0, 0);
        float* Od = Osf + s * 4224 + dsub * 528;
#pragma unroll
        for (int r = 0; r < 4; ++r) {
            Od[(hk * 4 + r) * 33 + lr]      = o0[r];
            Od[(hk * 4 + r) * 33 + 16 + lr] = o1[r];
        }
        if (ch & 1) {
            __syncthreads();
            int lidx = (t >> 5) * 33 + (t & 31);
            float4 q0, q1, q2, q3;
            q0.x = Osf[0 * 528 + lidx]; q0.y = Osf[1 * 528 + lidx];
            q0.z = Osf[2 * 528 + lidx]; q0.w = Osf[3 * 528 + lidx];
            q1.x = Osf[4 * 528 + lidx]; q1.y = Osf[5 * 528 + lidx];
            q1.z = Osf[6 * 528 + lidx]; q1.w = Osf[7 * 528 + lidx];
            q2.x = Osf[4224 + 0 * 528 + lidx]; q2.y = Osf[4224 + 1 * 528 + lidx];
            q2.z = Osf[4224 + 2 * 528 + lidx]; q2.w = Osf[4224 + 3 * 528 + lidx];
            q3.x = Osf[4224 + 4 * 528 + lidx]; q3.y = Osf[4224 + 5 * 528 + lidx];
            q3.z = Osf[4224 + 6 * 528 + lidx]; q3.w = Osf[4224 + 7 * 528 + lidx];
            float* po = out + obase0 + (ch >> 1) * 16;
            *reinterpret_cast<float4*>(po)      = q0;
            *reinterpret_cast<float4*>(po + 4)  = q1;
            *reinterpret_cast<float4*>(po + 8)  = q2;
            *reinterpret_cast<float4*>(po + 12) = q3;
            __syncthreads();
        }
    }
}

extern "C" void kernel_launch(void* const* d_in, const int* in_sizes, int n_in,
                              void* d_out, int out_size, void* d_ws, size_t ws_size,
                              hipStream_t stream) {
    const float* x     = (const float*)d_in[0];
    const float* w_sr  = (const float*)d_in[1];
    const float* b_sr  = (const float*)d_in[2];
    const float* Wq    = (const float*)d_in[3];
    const float* bq    = (const float*)d_in[4];
    const float* Wkv   = (const float*)d_in[5];
    const float* bkv   = (const float*)d_in[6];
    const float* gamma = (const float*)d_in[7];
    const float* beta  = (const float*)d_in[8];
    float* out = (float*)d_out;

    unsigned short* qb = (unsigned short*)d_ws;
    unsigned short* kb = qb + (size_t)50331648;
    unsigned short* vb = kb + (size_t)50331648;

    proj_mfma<<<2048, 512, 0, stream>>>(x, w_sr, b_sr, Wq, bq, Wkv, bkv, qb, kb, vb);

    attn_kernel<<<1024, 512, 0, stream>>>(qb, kb, vb, gamma, beta, out);
}

// Round 12
// 323.946 us; speedup vs baseline: 1.4287x; 1.0625x over previous
//
#include <hip/hip_runtime.h>
#include <stdint.h>
#include <stddef.h>

typedef __attribute__((ext_vector_type(8))) short short8;
typedef __attribute__((ext_vector_type(4))) float f32x4;

// ---- sizes ----
// x: (8, 64, 32, 32, 96) f32.  NH=4, hd=16, scale = 0.25
// intermediates q,k,v: bf16, per (b,o): d-plane layout [d=0..95][pos=h*32+w] (2KB planes)
#define PER_BO 98304            // 96 d * 1024 pos ushorts per (b,o)

__device__ __forceinline__ unsigned int cvtpk(float lo, float hi) {
    unsigned int r;
    asm("v_cvt_pk_bf16_f32 %0, %1, %2" : "=v"(r) : "v"(lo), "v"(hi));
    return r;
}

// ============================ Kernel 1: projection GEMM (MFMA) ============================
// Block = (b, h-row, d-group of 12). Decode: b = bidx&7 (-> XCD b), dg = (bidx>>3)&7,
// hrow = bidx>>6: the 8 dg-siblings sharing x-lines are 8 bidx apart = consecutive on one
// XCD -> co-resident -> shared 64B x-lines merge in L2 (fixes 1.83x read amplification).
// Stores: every 64B line of the d-plane output fully produced by one block.
__global__ __launch_bounds__(512, 2) void proj_mfma(
    const float* __restrict__ x, const float* __restrict__ w_sr, const float* __restrict__ b_sr,
    const float* __restrict__ Wq, const float* __restrict__ bq,
    const float* __restrict__ Wkv, const float* __restrict__ bkv,
    unsigned short* __restrict__ qb, unsigned short* __restrict__ kb, unsigned short* __restrict__ vb)
{
    __shared__ unsigned short Wh[12288];
    __shared__ float bl[192];
    __shared__ unsigned short Cb[2 * 6208];   // [buf][o_l: stride 388][m 384]

    int t = threadIdx.x;
    int bidx = blockIdx.x;
    int b = bidx & 7;
    int dg = (bidx >> 3) & 7;          // 0..7, d-group of 12
    int hrow = bidx >> 6;              // 0..31

    int lane = t & 63;
    int wvi = t >> 6;                  // 0..7; wave owns m-tiles wvi*3 .. wvi*3+2
    int lr = lane & 15, hk = lane >> 4;

    // ---- A: load x straight into registers (fragment layout) ----
    const float* xb = x + (size_t)b * 6291456 + hrow * 3072 + dg * 12;
    float af[3][16];
#pragma unroll
    for (int pi = 0; pi < 3; ++pi) {
        int m = (wvi * 3 + pi) * 16 + lr;
        int w = m / 12, dd = m - w * 12;
        const float* xp = xb + (size_t)(hk * 8) * 98304 + w * 96 + dd;
#pragma unroll
        for (int j = 0; j < 8; ++j) {
            af[pi][j]     = xp[(size_t)j * 98304];
            af[pi][8 + j] = xp[(size_t)(32 + j) * 98304];
        }
    }

    // ---- stage W_eff (bf16, swizzled) ----
#pragma unroll
    for (int i = 0; i < 6; ++i) {
        int qi = t + i * 512;
        int o = qi >> 4;
        int cq = qi & 15;
        int c = cq * 4;
        float4 wv4;
        if (o < 64) wv4 = *reinterpret_cast<const float4*>(Wq + o * 64 + c);
        else {
            wv4 = *reinterpret_cast<const float4*>(Wkv + (o - 64) * 64 + c);
            float4 sr = *reinterpret_cast<const float4*>(w_sr + c);
            wv4.x *= sr.x; wv4.y *= sr.y; wv4.z *= sr.z; wv4.w *= sr.w;
        }
        uint2 pk; pk.x = cvtpk(wv4.x, wv4.y); pk.y = cvtpk(wv4.z, wv4.w);
        int sw = (cq >> 1) ^ (o & 7);
        *reinterpret_cast<uint2*>(&Wh[o * 64 + sw * 8 + (cq & 1) * 4]) = pk;
    }
    if (t < 192) {
        float s;
        if (t < 64) s = bq[t];
        else {
            s = bkv[t - 64];
            for (int c = 0; c < 64; ++c) s += Wkv[(t - 64) * 64 + c] * b_sr[c];
        }
        bl[t] = s;
    }
    __syncthreads();

    // ---- convert A to hi/lo bf16 fragments ----
    short8 ahf[3][2], alf[3][2];
#pragma unroll
    for (int pi = 0; pi < 3; ++pi) {
#pragma unroll
        for (int half = 0; half < 2; ++half) {
            union { unsigned int u[4]; short8 v; } H, L;
#pragma unroll
            for (int q = 0; q < 4; ++q) {
                float f0 = af[pi][half * 8 + 2 * q];
                float f1 = af[pi][half * 8 + 2 * q + 1];
                unsigned int hp = cvtpk(f0, f1);
                float h0 = __uint_as_float(hp << 16);
                float h1 = __uint_as_float(hp & 0xffff0000u);
                H.u[q] = hp;
                L.u[q] = cvtpk(f0 - h0, f1 - h1);
            }
            ahf[pi][half] = H.v; alf[pi][half] = L.v;
        }
    }

    // ---- per-pt Cb write offsets: rows m0..m0+3 contiguous -> uint2 ----
    int wo[3];
#pragma unroll
    for (int pi = 0; pi < 3; ++pi)
        wo[pi] = lr * 388 + (wvi * 3 + pi) * 16 + hk * 4;

    // ---- stream-out decode: unit = 4 w at fixed (o, dd) = 8B, lanes contiguous ----
    int so_po[3], so_lo[3];
#pragma unroll
    for (int i = 0; i < 3; ++i) {
        int flat = i * 512 + t;        // 0..1535 = o_l(16) x dd(12) x w4(8)
        int o_l = flat / 96;
        int rem = flat - o_l * 96;
        int dd = rem >> 3;
        int w4 = rem & 7;
        so_po[i] = o_l * PER_BO + dd * 1024 + w4 * 4;
        so_lo[i] = o_l * 388 + w4 * 48 + dd;
    }

    float biasv[12];
#pragma unroll
    for (int ot = 0; ot < 12; ++ot) biasv[ot] = bl[ot * 16 + lr];

    f32x4 zero4 = {0.f, 0.f, 0.f, 0.f};
    int s7 = lr & 7;

#pragma unroll
    for (int ot = 0; ot < 12; ++ot) {
        unsigned short* cb = Cb + (ot & 1) * 6208;
        {
            int o = ot * 16 + lr;
            const unsigned short* wr = &Wh[o * 64];
            short8 b0 = *reinterpret_cast<const short8*>(wr + ((hk ^ s7) * 8));
            short8 b1 = *reinterpret_cast<const short8*>(wr + (((hk + 4) ^ s7) * 8));
            float bo = biasv[ot];
#pragma unroll
            for (int pi = 0; pi < 3; ++pi) {
                f32x4 acc = __builtin_amdgcn_mfma_f32_16x16x32_bf16(ahf[pi][0], b0, zero4, 0, 0, 0);
                acc = __builtin_amdgcn_mfma_f32_16x16x32_bf16(ahf[pi][1], b1, acc, 0, 0, 0);
                acc = __builtin_amdgcn_mfma_f32_16x16x32_bf16(alf[pi][0], b0, acc, 0, 0, 0);
                acc = __builtin_amdgcn_mfma_f32_16x16x32_bf16(alf[pi][1], b1, acc, 0, 0, 0);
                uint2 st;
                st.x = cvtpk(acc[0] + bo, acc[1] + bo);
                st.y = cvtpk(acc[2] + bo, acc[3] + bo);
                *reinterpret_cast<uint2*>(&cb[wo[pi]]) = st;
            }
        }
        __syncthreads();
        {
            int sel = ot >> 2;
            unsigned short* base =
                (sel == 0 ? qb : (sel == 1 ? kb : vb))
                + (size_t)(b * 64 + (ot & 3) * 16) * PER_BO + dg * 12288 + hrow * 32;
#pragma unroll
            for (int i = 0; i < 3; ++i) {
                const unsigned short* c = &cb[so_lo[i]];
                uint2 v;
                v.x = (unsigned int)c[0]  | ((unsigned int)c[12] << 16);
                v.y = (unsigned int)c[24] | ((unsigned int)c[36] << 16);
                *reinterpret_cast<uint2*>(base + so_po[i]) = v;
            }
        }
    }
}

// ============================ Kernel 2: attention (direct-reg, d-planes) ============================
// Verbatim R9 structure (measured ~127us): zero-barrier pass1 with direct coalesced frag reads,
// wave-private pass2 (V LDS transpose, no barriers), paired 64B out stores.
__global__ __launch_bounds__(512, 4) void attn_kernel(
    const unsigned short* __restrict__ qb, const unsigned short* __restrict__ kb,
    const unsigned short* __restrict__ vb,
    const float* __restrict__ gamma, const float* __restrict__ beta,
    float* __restrict__ out)
{
    __shared__ char smem[61440];
    unsigned short* Vw = (unsigned short*)smem;            // per-wave [w:32][h: stride 36]
    unsigned short* Pb = (unsigned short*)(smem + 18432);
    float* Osf  = (float*)(smem + 27648);                  // 2 bufs x 8 planes x 528
    float* lred = (float*)(smem + 27648);
    float* rlb  = (float*)(smem + 27648 + 16896);

    int t = threadIdx.x;
    int l = t & 63;
    int dsub = t >> 6;
    int lr = l & 15, hk = l >> 4;

    // XCD pair swizzle (both halves of (b,oc) on same XCD, concurrent)
    int id = blockIdx.x;
    int xcd = id & 7;
    int k7 = id >> 3;
    int p = xcd + 8 * (k7 >> 1);
    int half = k7 & 1;
    int oc = p & 63;
    int b = p >> 6;
    int n = oc >> 4;

    const unsigned short* qp = qb + (size_t)(b * 64 + oc) * PER_BO;
    const unsigned short* kp = kb + (size_t)(b * 64 + oc) * PER_BO;
    const unsigned short* vp = vb + (size_t)(b * 64 + oc) * PER_BO;

    float gm = gamma[n], bt = beta[n];
    float decv[8];
#pragma unroll
    for (int gb = 0; gb < 2; ++gb)
#pragma unroll
        for (int r = 0; r < 4; ++r) {
            int hh = half * 16 + hk * 4 + r;
            int gg = gb * 16 + lr;
            float dc = 2.0f * fabsf((float)(hh - gg)) * gm + bt;
            float sp = fmaxf(dc, 0.0f) + log1pf(__expf(-fabsf(dc)));
            decv[gb * 4 + r] = __expf(-sp);
        }

    const float scale = 0.25f;
    f32x4 zero4 = {0.f, 0.f, 0.f, 0.f};

    unsigned int ep[48];
    float lacc[8] = {0.f, 0.f, 0.f, 0.f, 0.f, 0.f, 0.f, 0.f};

    // ---------------- PASS 1: direct-reg QK^T -> E + partial l (no LDS, no barriers) ----------------
    int qoff  = half * 512 + lr * 32 + hk * 8;
    int koff0 = lr * 32 + hk * 8;
    int koff1 = koff0 + 512;

    uint4 qv[2], k0v[2], k1v[2];
    {
        int b0p = dsub * 1024;
        qv[0]  = *reinterpret_cast<const uint4*>(qp + b0p + qoff);
        k0v[0] = *reinterpret_cast<const uint4*>(kp + b0p + koff0);
        k1v[0] = *reinterpret_cast<const uint4*>(kp + b0p + koff1);
        int b1p = (8 + dsub) * 1024;
        qv[1]  = *reinterpret_cast<const uint4*>(qp + b1p + qoff);
        k0v[1] = *reinterpret_cast<const uint4*>(kp + b1p + koff0);
        k1v[1] = *reinterpret_cast<const uint4*>(kp + b1p + koff1);
    }

#pragma unroll
    for (int ch = 0; ch < 12; ++ch) {
        int s = ch & 1;
        union { uint4 u; short8 v; } A, B0, B1;
        A.u = qv[s]; B0.u = k0v[s]; B1.u = k1v[s];
        f32x4 s0 = __builtin_amdgcn_mfma_f32_16x16x32_bf16(A.v, B0.v, zero4, 0, 0, 0);
        f32x4 s1 = __builtin_amdgcn_mfma_f32_16x16x32_bf16(A.v, B1.v, zero4, 0, 0, 0);
        if (ch < 10) {
            int bp = ((ch + 2) * 8 + dsub) * 1024;
            qv[s]  = *reinterpret_cast<const uint4*>(qp + bp + qoff);
            k0v[s] = *reinterpret_cast<const uint4*>(kp + bp + koff0);
            k1v[s] = *reinterpret_cast<const uint4*>(kp + bp + koff1);
        }
        float e[8];
#pragma unroll
        for (int r = 0; r < 4; ++r) {
            e[r]     = __expf(s0[r] * scale + decv[r]);
            e[4 + r] = __expf(s1[r] * scale + decv[4 + r]);
        }
#pragma unroll
        for (int i = 0; i < 8; ++i) lacc[i] += e[i];
        ep[ch * 4 + 0] = cvtpk(e[0], e[1]);
        ep[ch * 4 + 1] = cvtpk(e[2], e[3]);
        ep[ch * 4 + 2] = cvtpk(e[4], e[5]);
        ep[ch * 4 + 3] = cvtpk(e[6], e[7]);
    }

    // ---------------- l reduction (only cross-wave communication) ----------------
#pragma unroll
    for (int i = 0; i < 8; ++i)
        lred[dsub * 528 + (hk * 4 + (i & 3)) * 33 + (i >> 2) * 16 + lr] = lacc[i];
    __syncthreads();
    {
        float rsum = 0.f;
#pragma unroll
        for (int s = 0; s < 8; ++s) rsum += lred[s * 528 + (t >> 5) * 33 + (t & 31)];
        rlb[(t >> 5) * 33 + (t & 31)] = 1.0f / rsum;
    }
    __syncthreads();
    float rl8[8];
#pragma unroll
    for (int i = 0; i < 8; ++i)
        rl8[i] = rlb[(hk * 4 + (i & 3)) * 33 + (i >> 2) * 16 + lr];
    __syncthreads();

    // ---------------- PASS 2: wave-private V stage + P -> PV -> out ----------------
    int vgoff = l * 16;
    int vwbase = dsub * 1152 + ((l & 1) * 16) * 36 + (l >> 1);
    unsigned short* Pw = Pb + dsub * 576;

    uint4 vv0[2], vv1[2];
    {
        int b0p = dsub * 1024 + vgoff;
        vv0[0] = *reinterpret_cast<const uint4*>(vp + b0p);
        vv1[0] = *reinterpret_cast<const uint4*>(vp + b0p + 8);
        int b1p = (8 + dsub) * 1024 + vgoff;
        vv0[1] = *reinterpret_cast<const uint4*>(vp + b1p);
        vv1[1] = *reinterpret_cast<const uint4*>(vp + b1p + 8);
    }

    size_t obase0 = ((size_t)(b * 64 + oc) * 1024 + half * 512 + t) * 96;

#pragma unroll
    for (int ch = 0; ch < 12; ++ch) {
        int s = ch & 1;
        {
            union { uint4 u; unsigned short e[8]; } V0, V1;
            V0.u = vv0[s]; V1.u = vv1[s];
#pragma unroll
            for (int i = 0; i < 8; ++i) Vw[vwbase + i * 36] = V0.e[i];
#pragma unroll
            for (int i = 0; i < 8; ++i) Vw[vwbase + (i + 8) * 36] = V1.e[i];
        }
#pragma unroll
        for (int gb = 0; gb < 2; ++gb)
#pragma unroll
            for (int rp = 0; rp < 2; ++rp) {
                unsigned int u = ep[ch * 4 + gb * 2 + rp];
                float p0 = __uint_as_float(u << 16)         * rl8[gb * 4 + rp * 2];
                float p1 = __uint_as_float(u & 0xffff0000u) * rl8[gb * 4 + rp * 2 + 1];
                unsigned int pk = cvtpk(p0, p1);
                Pw[(hk * 4 + rp * 2) * 36 + gb * 16 + lr]     = (unsigned short)pk;
                Pw[(hk * 4 + rp * 2 + 1) * 36 + gb * 16 + lr] = (unsigned short)(pk >> 16);
            }
        if (ch < 10) {
            int bp = ((ch + 2) * 8 + dsub) * 1024 + vgoff;
            vv0[s] = *reinterpret_cast<const uint4*>(vp + bp);
            vv1[s] = *reinterpret_cast<const uint4*>(vp + bp + 8);
        }
        asm volatile("s_waitcnt lgkmcnt(0)" ::: "memory");
        __builtin_amdgcn_sched_barrier(0);
        short8 pa  = *reinterpret_cast<const short8*>(Pw + lr * 36 + hk * 8);
        short8 vb0 = *reinterpret_cast<const short8*>(Vw + dsub * 1152 + lr * 36 + hk * 8);
        short8 vb1 = *reinterpret_cast<const short8*>(Vw + dsub * 1152 + (16 + lr) * 36 + hk * 8);
        f32x4 o0 = __builtin_amdgcn_mfma_f32_16x16x32_bf16(pa, vb0, zero4, 0, 0, 0);
        f32x4 o1 = __builtin_amdgcn_mfma_f32_16x16x32_bf16(pa, vb1, zero4, 0, 0, 0);
        float* Od = Osf + s * 4224 + dsub * 528;
#pragma unroll
        for (int r = 0; r < 4; ++r) {
            Od[(hk * 4 + r) * 33 + lr]      = o0[r];
            Od[(hk * 4 + r) * 33 + 16 + lr] = o1[r];
        }
        if (ch & 1) {
            __syncthreads();
            int lidx = (t >> 5) * 33 + (t & 31);
            float4 q0, q1, q2, q3;
            q0.x = Osf[0 * 528 + lidx]; q0.y = Osf[1 * 528 + lidx];
            q0.z = Osf[2 * 528 + lidx]; q0.w = Osf[3 * 528 + lidx];
            q1.x = Osf[4 * 528 + lidx]; q1.y = Osf[5 * 528 + lidx];
            q1.z = Osf[6 * 528 + lidx]; q1.w = Osf[7 * 528 + lidx];
            q2.x = Osf[4224 + 0 * 528 + lidx]; q2.y = Osf[4224 + 1 * 528 + lidx];
            q2.z = Osf[4224 + 2 * 528 + lidx]; q2.w = Osf[4224 + 3 * 528 + lidx];
            q3.x = Osf[4224 + 4 * 528 + lidx]; q3.y = Osf[4224 + 5 * 528 + lidx];
            q3.z = Osf[4224 + 6 * 528 + lidx]; q3.w = Osf[4224 + 7 * 528 + lidx];
            float* po = out + obase0 + (ch >> 1) * 16;
            *reinterpret_cast<float4*>(po)      = q0;
            *reinterpret_cast<float4*>(po + 4)  = q1;
            *reinterpret_cast<float4*>(po + 8)  = q2;
            *reinterpret_cast<float4*>(po + 12) = q3;
            __syncthreads();
        }
    }
}

extern "C" void kernel_launch(void* const* d_in, const int* in_sizes, int n_in,
                              void* d_out, int out_size, void* d_ws, size_t ws_size,
                              hipStream_t stream) {
    const float* x     = (const float*)d_in[0];
    const float* w_sr  = (const float*)d_in[1];
    const float* b_sr  = (const float*)d_in[2];
    const float* Wq    = (const float*)d_in[3];
    const float* bq    = (const float*)d_in[4];
    const float* Wkv   = (const float*)d_in[5];
    const float* bkv   = (const float*)d_in[6];
    const float* gamma = (const float*)d_in[7];
    const float* beta  = (const float*)d_in[8];
    float* out = (float*)d_out;

    unsigned short* qb = (unsigned short*)d_ws;
    unsigned short* kb = qb + (size_t)50331648;
    unsigned short* vb = kb + (size_t)50331648;

    proj_mfma<<<2048, 512, 0, stream>>>(x, w_sr, b_sr, Wq, bq, Wkv, bkv, qb, kb, vb);

    attn_kernel<<<1024, 512, 0, stream>>>(qb, kb, vb, gamma, beta, out);
}